// Round 1
// baseline (461.337 us; speedup 1.0000x reference)
//
#include <hip/hip_runtime.h>
#include <math.h>

#define LSEQ 4096   // D*H*W = 16*16*16
#define CIN  128
#define DI   64     // d_inner
#define NS   16     // d_state
#define NP   4      // parts
#define NJ   4      // jobs = (b, mixer) pairs: (0,0),(0,e0),(1,0),(1,e1)
#define NSEQ 16     // NJ * NP independent mamba sequences
#define NC   32     // scan chunks
#define LC   128    // chunk length (NC*LC = LSEQ)

__device__ __forceinline__ int mixer_of(const int* did, int j){
  if((j&1)==0) return 0;
  int d = did[j>>1];
  return 1 + (d < 1 ? d : 1);
}
__device__ __forceinline__ float silu_f(float x){ return x/(1.f+expf(-x)); }

// ---------------- K1: LayerNorm1 + in_proj (per l, per job) ----------------
__global__ __launch_bounds__(128) void k1_ln_inproj(
  const float* __restrict__ x, const int* __restrict__ did,
  const float* __restrict__ ln_g, const float* __restrict__ ln_b,
  const float* __restrict__ in_w,
  float* __restrict__ xnb, float* __restrict__ xzr, float* __restrict__ zb)
{
  const int l = blockIdx.x, j = blockIdx.y, b = j>>1, t = threadIdx.x;
  const int m = mixer_of(did, j);
  __shared__ float s_wT[32*128];
  __shared__ float s_xn[128];
  __shared__ float red[128];
  for(int i=t;i<4096;i+=128){ s_wT[(i&31)*128+(i>>5)] = in_w[m*4096+i]; }
  float xv = x[((size_t)b*CIN+t)*LSEQ + l];
  red[t]=xv; __syncthreads();
  for(int off=64;off;off>>=1){ if(t<off) red[t]+=red[t+off]; __syncthreads(); }
  float mu = red[0]*(1.f/128.f); __syncthreads();
  float dv = xv-mu; red[t]=dv*dv; __syncthreads();
  for(int off=64;off;off>>=1){ if(t<off) red[t]+=red[t+off]; __syncthreads(); }
  float rs = rsqrtf(red[0]*(1.f/128.f)+1e-5f);
  float xnv = dv*rs*ln_g[m*128+t]+ln_b[m*128+t];
  s_xn[t]=xnv;
  xnb[((size_t)j*LSEQ+l)*128+t]=xnv;
  __syncthreads();
  #pragma unroll
  for(int q=0;q<4;q++){      // q = part; e = t in [0,128)
    float acc=0.f;
    #pragma unroll
    for(int d=0;d<32;d++) acc += s_xn[q*32+d]*s_wT[d*128+t];
    size_t base = ((size_t)(j*NP+q)*LSEQ + l)*64;
    if(t<64) xzr[base+t]=acc; else zb[base+t-64]=acc;
  }
}

// ---------- K2: causal depthwise conv + SiLU + x_proj + dt_proj/softplus ----------
__global__ __launch_bounds__(256) void k2_conv_xproj(
  const int* __restrict__ did,
  const float* __restrict__ conv_w, const float* __restrict__ conv_b,
  const float* __restrict__ xp_w, const float* __restrict__ dt_w, const float* __restrict__ dt_b,
  const float* __restrict__ xzr, float* __restrict__ xib, float* __restrict__ dlb,
  float* __restrict__ bmb, float* __restrict__ cmb)
{
  const int seq = blockIdx.y, j = seq>>2, t = threadIdx.x;
  const int li = t>>6, d = t&63;
  const int l = blockIdx.x*4 + li;
  const int m = mixer_of(did, j);
  __shared__ float s_xi[4][64];
  __shared__ float s_dbc[4][2];
  __shared__ float s_xpw[34*65];
  __shared__ float s_cw[256], s_cb[64], s_dtw[128], s_dtb[64];
  for(int i=t;i<34*64;i+=256) s_xpw[(i>>6)*65+(i&63)] = xp_w[m*2176+i];
  s_cw[t]=conv_w[m*256+t];
  if(t<64){ s_cb[t]=conv_b[m*64+t]; s_dtb[t]=dt_b[m*64+t]; }
  if(t<128) s_dtw[t]=dt_w[m*128+t];
  __syncthreads();
  const float* xz = xzr + (size_t)seq*LSEQ*64;
  float xc = s_cb[d];
  #pragma unroll
  for(int k=0;k<4;k++){ int ll=l-3+k; if(ll>=0) xc += xz[(size_t)ll*64+d]*s_cw[d*4+k]; }
  float xiv = silu_f(xc);
  xib[(size_t)seq*LSEQ*64 + (size_t)l*64 + d] = xiv;
  s_xi[li][d]=xiv;
  __syncthreads();
  if(d<34){
    float acc=0.f;
    #pragma unroll
    for(int dd=0;dd<64;dd++) acc += s_xi[li][dd]*s_xpw[d*65+dd];
    if(d<2) s_dbc[li][d]=acc;
    else if(d<18) bmb[((size_t)seq*LSEQ+l)*16 + d-2]=acc;
    else          cmb[((size_t)seq*LSEQ+l)*16 + d-18]=acc;
  }
  __syncthreads();
  float dtv = s_dbc[li][0]*s_dtw[d*2] + s_dbc[li][1]*s_dtw[d*2+1] + s_dtb[d];
  float dlv = dtv>20.f ? dtv : log1pf(expf(dtv));
  dlb[(size_t)seq*LSEQ*64 + (size_t)l*64 + d] = dlv;
}

// ---------------- K3a: per-chunk local scan -> (P = prod dA, E = local end state) ----------------
__global__ __launch_bounds__(1024) void k3a_scan_pe(
  const int* __restrict__ did, const float* __restrict__ A_log,
  const float* __restrict__ xib, const float* __restrict__ dlb, const float* __restrict__ bmb,
  float* __restrict__ pb, float* __restrict__ eb)
{
  const int chunk=blockIdx.x, seq=blockIdx.y, j=seq>>2, t=threadIdx.x;
  const int d=t>>4, s=t&15;
  const int m=mixer_of(did,j);
  const float a = -expf(A_log[m*1024 + d*16 + s]);
  const float* dp = dlb + (size_t)seq*LSEQ*64 + (size_t)chunk*LC*64;
  const float* xp = xib + (size_t)seq*LSEQ*64 + (size_t)chunk*LC*64;
  const float* bp = bmb + (size_t)seq*LSEQ*16 + (size_t)chunk*LC*16;
  float P=1.f, E=0.f;
  #pragma unroll 4
  for(int i=0;i<LC;i++){
    float dl=dp[i*64+d], xiv=xp[i*64+d], bv=bp[i*16+s];
    float dA=expf(dl*a);
    P*=dA;
    E=fmaf(dA,E, dl*xiv*bv);
  }
  size_t o=((size_t)seq*NC+chunk)*1024 + t;
  pb[o]=P; eb[o]=E;
}

// ---------------- K3b: combine chunk summaries -> per-chunk start state ----------------
__global__ __launch_bounds__(1024) void k3b_combine(
  const float* __restrict__ pb, const float* __restrict__ eb, float* __restrict__ hsb)
{
  const int seq=blockIdx.x, t=threadIdx.x;
  float h=0.f;
  for(int c=0;c<NC;c++){
    size_t o=((size_t)seq*NC+c)*1024+t;
    hsb[o]=h;
    h=fmaf(pb[o],h,eb[o]);
  }
}

// ---------------- K3c: full scan with correct h0, produce y ----------------
__global__ __launch_bounds__(1024) void k3c_scan_y(
  const int* __restrict__ did, const float* __restrict__ A_log,
  const float* __restrict__ xib, const float* __restrict__ dlb,
  const float* __restrict__ bmb, const float* __restrict__ cmb,
  const float* __restrict__ hsb, float* __restrict__ yb)
{
  const int chunk=blockIdx.x, seq=blockIdx.y, j=seq>>2, t=threadIdx.x;
  const int d=t>>4, s=t&15;
  const int m=mixer_of(did,j);
  const float a=-expf(A_log[m*1024+d*16+s]);
  const float* dp=dlb+(size_t)seq*LSEQ*64+(size_t)chunk*LC*64;
  const float* xp=xib+(size_t)seq*LSEQ*64+(size_t)chunk*LC*64;
  const float* bp=bmb+(size_t)seq*LSEQ*16+(size_t)chunk*LC*16;
  const float* cp=cmb+(size_t)seq*LSEQ*16+(size_t)chunk*LC*16;
  float h=hsb[((size_t)seq*NC+chunk)*1024+t];
  float* yo=yb+(size_t)seq*LSEQ*64+(size_t)chunk*LC*64;
  #pragma unroll 4
  for(int i=0;i<LC;i++){
    float dl=dp[i*64+d], xiv=xp[i*64+d], bv=bp[i*16+s], cv=cp[i*16+s];
    float dA=expf(dl*a);
    h=fmaf(dA,h, dl*xiv*bv);
    float yv=h*cv;
    yv+=__shfl_xor(yv,1); yv+=__shfl_xor(yv,2); yv+=__shfl_xor(yv,4); yv+=__shfl_xor(yv,8);
    if(s==0) yo[i*64+d]=yv;
  }
}

// ---------------- K4: y + Dp*xi, gate with silu(z), out_proj, +skip*xn -> xm ----------------
__global__ __launch_bounds__(256) void k4_gate_outproj(
  const int* __restrict__ did, const float* __restrict__ Dp, const float* __restrict__ out_w,
  const float* __restrict__ skipv, const float* __restrict__ yb, const float* __restrict__ xib,
  const float* __restrict__ zb, const float* __restrict__ xnb, float* __restrict__ xmb)
{
  const int seq=blockIdx.y, j=seq>>2, p=seq&3, t=threadIdx.x;
  const int li=t>>6, q=t&63;
  const int l=blockIdx.x*4+li;
  const int m=mixer_of(did,j);
  __shared__ float s_yg[4][64];
  __shared__ float s_ow[32*65];
  for(int i=t;i<2048;i+=256) s_ow[(i>>6)*65+(i&63)]=out_w[m*2048+i];
  size_t base=(size_t)seq*LSEQ*64 + (size_t)l*64+q;
  float yv=yb[base], xiv=xib[base], zv=zb[base];
  float yg=(yv+Dp[m*64+q]*xiv)*silu_f(zv);
  s_yg[li][q]=yg;
  __syncthreads();
  if(q<32){
    float acc=0.f;
    #pragma unroll
    for(int dd=0;dd<64;dd++) acc+=s_yg[li][dd]*s_ow[q*65+dd];
    size_t xidx=((size_t)j*LSEQ+l)*128+p*32+q;
    xmb[xidx]=acc+skipv[m]*xnb[xidx];
  }
}

// ---------------- K5: LayerNorm2 + proj, sum shared+expert, write output ----------------
__global__ __launch_bounds__(128) void k5_ln2_proj(
  const int* __restrict__ did, const float* __restrict__ ln_g, const float* __restrict__ ln_b,
  const float* __restrict__ proj_w, const float* __restrict__ proj_b,
  const float* __restrict__ xmb, float* __restrict__ out)
{
  const int l=blockIdx.x, b=blockIdx.y, t=threadIdx.x;
  __shared__ float s_x[128];
  __shared__ float red[128];
  float acc=0.f;
  for(int e=0;e<2;e++){
    int j=b*2+e; int m=mixer_of(did,j);
    float xv=xmb[((size_t)j*LSEQ+l)*128+t];
    red[t]=xv; __syncthreads();
    for(int off=64;off;off>>=1){ if(t<off) red[t]+=red[t+off]; __syncthreads(); }
    float mu=red[0]*(1.f/128.f); __syncthreads();
    float dv=xv-mu; red[t]=dv*dv; __syncthreads();
    for(int off=64;off;off>>=1){ if(t<off) red[t]+=red[t+off]; __syncthreads(); }
    float rs=rsqrtf(red[0]*(1.f/128.f)+1e-5f); __syncthreads();
    s_x[t]=dv*rs*ln_g[m*128+t]+ln_b[m*128+t];
    __syncthreads();
    float pa=proj_b[m*128+t];
    const float* pw = proj_w + (size_t)m*16384 + (size_t)t*128;
    #pragma unroll 8
    for(int c=0;c<128;c++) pa += s_x[c]*pw[c];
    acc+=pa;
    __syncthreads();
  }
  out[((size_t)b*128+t)*LSEQ + l]=acc;
}

extern "C" void kernel_launch(void* const* d_in, const int* in_sizes, int n_in,
                              void* d_out, int out_size, void* d_ws, size_t ws_size,
                              hipStream_t stream) {
  const float* x      = (const float*)d_in[0];
  const int*   did    = (const int*)d_in[1];
  const float* ln_g   = (const float*)d_in[2];
  const float* ln_b   = (const float*)d_in[3];
  const float* in_w   = (const float*)d_in[4];
  const float* conv_w = (const float*)d_in[5];
  const float* conv_b = (const float*)d_in[6];
  const float* xp_w   = (const float*)d_in[7];
  const float* dt_w   = (const float*)d_in[8];
  const float* dt_b   = (const float*)d_in[9];
  const float* A_log  = (const float*)d_in[10];
  const float* Dp     = (const float*)d_in[11];
  const float* out_w  = (const float*)d_in[12];
  const float* proj_w = (const float*)d_in[13];
  const float* proj_b = (const float*)d_in[14];
  const float* skipv  = (const float*)d_in[15];
  float* out = (float*)d_out;
  float* ws  = (float*)d_ws;

  float* xnb = ws;                                   // NJ*L*128
  float* xzr = xnb + (size_t)NJ*LSEQ*128;            // NSEQ*L*64 (xi pre-conv; reused as y)
  float* zb  = xzr + (size_t)NSEQ*LSEQ*64;           // NSEQ*L*64
  float* xib = zb  + (size_t)NSEQ*LSEQ*64;           // NSEQ*L*64 (xi post conv+silu)
  float* dlb = xib + (size_t)NSEQ*LSEQ*64;           // NSEQ*L*64 (delta)
  float* bmb = dlb + (size_t)NSEQ*LSEQ*64;           // NSEQ*L*16
  float* cmb = bmb + (size_t)NSEQ*LSEQ*16;           // NSEQ*L*16
  float* xmb = cmb + (size_t)NSEQ*LSEQ*16;           // NJ*L*128
  float* pb  = xmb + (size_t)NJ*LSEQ*128;            // NSEQ*NC*1024
  float* eb  = pb  + (size_t)NSEQ*NC*1024;           // NSEQ*NC*1024
  float* hsb = eb  + (size_t)NSEQ*NC*1024;           // NSEQ*NC*1024
  float* yb  = xzr;                                  // reuse (xzr dead after k2)

  hipLaunchKernelGGL(k1_ln_inproj, dim3(LSEQ,NJ), dim3(128), 0, stream,
                     x,did,ln_g,ln_b,in_w,xnb,xzr,zb);
  hipLaunchKernelGGL(k2_conv_xproj, dim3(LSEQ/4,NSEQ), dim3(256), 0, stream,
                     did,conv_w,conv_b,xp_w,dt_w,dt_b,xzr,xib,dlb,bmb,cmb);
  hipLaunchKernelGGL(k3a_scan_pe, dim3(NC,NSEQ), dim3(1024), 0, stream,
                     did,A_log,xib,dlb,bmb,pb,eb);
  hipLaunchKernelGGL(k3b_combine, dim3(NSEQ), dim3(1024), 0, stream, pb,eb,hsb);
  hipLaunchKernelGGL(k3c_scan_y, dim3(NC,NSEQ), dim3(1024), 0, stream,
                     did,A_log,xib,dlb,bmb,cmb,hsb,yb);
  hipLaunchKernelGGL(k4_gate_outproj, dim3(LSEQ/4,NSEQ), dim3(256), 0, stream,
                     did,Dp,out_w,skipv,yb,xib,zb,xnb,xmb);
  hipLaunchKernelGGL(k5_ln2_proj, dim3(LSEQ,2), dim3(128), 0, stream,
                     did,ln_g,ln_b,proj_w,proj_b,xmb,out);
}

// Round 2
// 221.514 us; speedup vs baseline: 2.0827x; 2.0827x over previous
//
#include <hip/hip_runtime.h>
#include <math.h>

#define LSEQ 4096   // D*H*W = 16*16*16
#define CIN  128
#define DI   64     // d_inner
#define NS   16     // d_state
#define NP   4      // parts
#define NJ   4      // jobs = (b, mixer) pairs
#define NSEQ 16     // NJ * NP independent mamba sequences
#define NC   32     // scan chunks
#define LC   128    // chunk length (NC*LC = LSEQ)

__device__ __forceinline__ int mixer_of(const int* did, int j){
  if((j&1)==0) return 0;
  int d = did[j>>1];
  return 1 + (d < 1 ? d : 1);
}
__device__ __forceinline__ float silu_f(float x){ return x/(1.f+expf(-x)); }

// ---------------- K1: LN1 + in_proj. 32 l per block, w rows in registers ----------------
__global__ __launch_bounds__(256) void k1_ln_inproj(
  const float* __restrict__ x, const int* __restrict__ did,
  const float* __restrict__ ln_g, const float* __restrict__ ln_b,
  const float* __restrict__ in_w,
  float* __restrict__ xnb, float* __restrict__ xzr, float* __restrict__ zb)
{
  const int j = blockIdx.y, b = j>>1, t = threadIdx.x;
  const int l0 = blockIdx.x*32;
  const int m = mixer_of(did, j);
  __shared__ float s_x[128][33];    // [c][ll]  bank=(c+ll)%32
  __shared__ float s_xn[32][132];   // [ll][c]  bank=(4ll+c)%32, rows 16B-aligned
  __shared__ float s_mu[32], s_rs[32];

  // x tile load (coalesced 128B rows; conflict-free stores)
  for(int idx=t; idx<4096; idx+=256){
    int c = idx>>5, ll = idx&31;
    s_x[c][ll] = x[((size_t)b*CIN+c)*LSEQ + l0+ll];
  }
  // per-thread weight row e=t&127 (same row serves all 4 parts)
  float wreg[32];
  {
    const float4* wp = (const float4*)(in_w + (size_t)m*4096 + (size_t)(t&127)*32);
    #pragma unroll
    for(int i=0;i<8;i++){
      float4 v = wp[i];
      wreg[i*4+0]=v.x; wreg[i*4+1]=v.y; wreg[i*4+2]=v.z; wreg[i*4+3]=v.w;
    }
  }
  __syncthreads();

  // LayerNorm stats: 4 waves x 8 l; lane = lw*8+g, g sums 16 channels
  {
    const int wv = t>>6, lane = t&63;
    const int g = lane&7, lw = lane>>3;
    const int ll = wv*8+lw;
    float sum=0.f;
    #pragma unroll
    for(int k=0;k<16;k++) sum += s_x[g*16+k][ll];
    sum += __shfl_xor(sum,1); sum += __shfl_xor(sum,2); sum += __shfl_xor(sum,4);
    float mu = sum*(1.f/128.f);
    float vs=0.f;
    #pragma unroll
    for(int k=0;k<16;k++){ float dv = s_x[g*16+k][ll]-mu; vs += dv*dv; }
    vs += __shfl_xor(vs,1); vs += __shfl_xor(vs,2); vs += __shfl_xor(vs,4);
    if(g==0){ s_mu[ll]=mu; s_rs[ll]=rsqrtf(vs*(1.f/128.f)+1e-5f); }
  }
  __syncthreads();

  // normalize -> s_xn [ll][c] + global xnb (coalesced per l row)
  for(int idx=t; idx<4096; idx+=256){
    int ll = idx>>7, c = idx&127;
    float xn = (s_x[c][ll]-s_mu[ll])*s_rs[ll]*ln_g[m*128+c] + ln_b[m*128+c];
    s_xn[ll][c] = xn;
    xnb[((size_t)j*LSEQ + l0+ll)*128 + c] = xn;
  }
  __syncthreads();

  // in_proj: thread e=t&127, half hh covers 16 l; xn reads are wave-uniform broadcasts
  const int e = t&127, hh = t>>7;
  for(int ll=hh*16; ll<hh*16+16; ++ll){
    const float* xr = &s_xn[ll][0];
    #pragma unroll
    for(int q=0;q<4;q++){
      float acc=0.f;
      #pragma unroll
      for(int d=0;d<32;d++) acc += xr[q*32+d]*wreg[d];
      size_t base = ((size_t)(j*NP+q)*LSEQ + l0+ll)*64;
      if(e<64) xzr[base+e]=acc; else zb[base+e-64]=acc;
    }
  }
}

// ---------- K2: conv + SiLU + x_proj + dt/softplus. 64 l per block ----------
__global__ __launch_bounds__(256) void k2_conv_xproj(
  const int* __restrict__ did,
  const float* __restrict__ conv_w, const float* __restrict__ conv_b,
  const float* __restrict__ xp_w, const float* __restrict__ dt_w, const float* __restrict__ dt_b,
  const float* __restrict__ xzr, float* __restrict__ xib, float* __restrict__ dlb,
  float* __restrict__ bmb, float* __restrict__ cmb)
{
  const int seq = blockIdx.y, j = seq>>2, t = threadIdx.x;
  const int l0 = blockIdx.x*64;
  const int m = mixer_of(did, j);
  __shared__ float s_xz[67][64];    // rows l0-3 .. l0+63
  __shared__ float s_xi[64][64];    // post conv+silu
  __shared__ float s_xpw[34][65];
  __shared__ float s_cwT[4][64];
  __shared__ float s_cb[64], s_dtw[128], s_dtb[64];
  __shared__ float s_dbc[64][2];

  for(int idx=t; idx<67*64; idx+=256){
    int row = idx>>6, d = idx&63, l = l0-3+row;
    s_xz[row][d] = (l>=0) ? xzr[((size_t)seq*LSEQ + l)*64 + d] : 0.f;
  }
  for(int idx=t; idx<34*64; idx+=256){
    int o = idx>>6, d = idx&63;
    s_xpw[o][d] = xp_w[m*2176 + idx];
  }
  if(t<256){ int k = t>>6, d = t&63; s_cwT[k][d] = conv_w[m*256 + d*4 + k]; }
  if(t<64){ s_cb[t]=conv_b[m*64+t]; s_dtb[t]=dt_b[m*64+t]; }
  if(t<128) s_dtw[t]=dt_w[m*128+t];
  __syncthreads();

  // conv: 16 (l,d) pairs per thread
  for(int it=0; it<16; ++it){
    int idx = t + it*256;
    int ll = idx>>6, d = idx&63;
    float xc = s_cb[d];
    #pragma unroll
    for(int k=0;k<4;k++) xc += s_xz[ll+k][d]*s_cwT[k][d];
    float xiv = silu_f(xc);
    s_xi[ll][d]=xiv;
    xib[(size_t)seq*LSEQ*64 + (size_t)(l0+ll)*64 + d] = xiv;
  }
  __syncthreads();

  // x_proj: o = t&63 (o<34 active), 16 l per thread-group
  {
    const int o = t&63, lg = t>>6;
    for(int ll=lg; ll<64; ll+=4){
      if(o<34){
        float acc=0.f;
        #pragma unroll
        for(int dd=0;dd<64;dd++) acc += s_xi[ll][dd]*s_xpw[o][dd];
        if(o<2) s_dbc[ll][o]=acc;
        else if(o<18) bmb[((size_t)seq*LSEQ + l0+ll)*16 + o-2]=acc;
        else          cmb[((size_t)seq*LSEQ + l0+ll)*16 + o-18]=acc;
      }
    }
  }
  __syncthreads();

  // dt proj + softplus
  for(int it=0; it<16; ++it){
    int idx = t + it*256;
    int ll = idx>>6, d = idx&63;
    float dtv = s_dbc[ll][0]*s_dtw[d*2] + s_dbc[ll][1]*s_dtw[d*2+1] + s_dtb[d];
    float dlv = dtv>20.f ? dtv : log1pf(expf(dtv));
    dlb[(size_t)seq*LSEQ*64 + (size_t)(l0+ll)*64 + d] = dlv;
  }
}

// ---------------- K3a: per-chunk (P = prod dA, E = local end state) ----------------
__global__ __launch_bounds__(1024) void k3a_scan_pe(
  const int* __restrict__ did, const float* __restrict__ A_log,
  const float* __restrict__ xib, const float* __restrict__ dlb, const float* __restrict__ bmb,
  float* __restrict__ pb, float* __restrict__ eb)
{
  const int chunk=blockIdx.x, seq=blockIdx.y, j=seq>>2, t=threadIdx.x;
  const int d=t>>4, s=t&15;
  const int m=mixer_of(did,j);
  const float a = -expf(A_log[m*1024 + d*16 + s]);
  const float* dp = dlb + (size_t)seq*LSEQ*64 + (size_t)chunk*LC*64;
  const float* xp = xib + (size_t)seq*LSEQ*64 + (size_t)chunk*LC*64;
  const float* bp = bmb + (size_t)seq*LSEQ*16 + (size_t)chunk*LC*16;
  float P=1.f, E=0.f;
  #pragma unroll 4
  for(int i=0;i<LC;i++){
    float dl=dp[i*64+d], xiv=xp[i*64+d], bv=bp[i*16+s];
    float dA=expf(dl*a);
    P*=dA;
    E=fmaf(dA,E, dl*xiv*bv);
  }
  size_t o=((size_t)seq*NC+chunk)*1024 + t;
  pb[o]=P; eb[o]=E;
}

// ---------------- K3b: combine chunk summaries ----------------
__global__ __launch_bounds__(1024) void k3b_combine(
  const float* __restrict__ pb, const float* __restrict__ eb, float* __restrict__ hsb)
{
  const int seq=blockIdx.x, t=threadIdx.x;
  float h=0.f;
  #pragma unroll
  for(int c=0;c<NC;c++){
    size_t o=((size_t)seq*NC+c)*1024+t;
    hsb[o]=h;
    h=fmaf(pb[o],h,eb[o]);
  }
}

// ---------------- K3c: full scan with correct h0, produce y ----------------
__global__ __launch_bounds__(1024) void k3c_scan_y(
  const int* __restrict__ did, const float* __restrict__ A_log,
  const float* __restrict__ xib, const float* __restrict__ dlb,
  const float* __restrict__ bmb, const float* __restrict__ cmb,
  const float* __restrict__ hsb, float* __restrict__ yb)
{
  const int chunk=blockIdx.x, seq=blockIdx.y, j=seq>>2, t=threadIdx.x;
  const int d=t>>4, s=t&15;
  const int m=mixer_of(did,j);
  const float a=-expf(A_log[m*1024+d*16+s]);
  const float* dp=dlb+(size_t)seq*LSEQ*64+(size_t)chunk*LC*64;
  const float* xp=xib+(size_t)seq*LSEQ*64+(size_t)chunk*LC*64;
  const float* bp=bmb+(size_t)seq*LSEQ*16+(size_t)chunk*LC*16;
  const float* cp=cmb+(size_t)seq*LSEQ*16+(size_t)chunk*LC*16;
  float h=hsb[((size_t)seq*NC+chunk)*1024+t];
  float* yo=yb+(size_t)seq*LSEQ*64+(size_t)chunk*LC*64;
  #pragma unroll 4
  for(int i=0;i<LC;i++){
    float dl=dp[i*64+d], xiv=xp[i*64+d], bv=bp[i*16+s], cv=cp[i*16+s];
    float dA=expf(dl*a);
    h=fmaf(dA,h, dl*xiv*bv);
    float yv=h*cv;
    yv+=__shfl_xor(yv,1); yv+=__shfl_xor(yv,2); yv+=__shfl_xor(yv,4); yv+=__shfl_xor(yv,8);
    if(s==0) yo[i*64+d]=yv;
  }
}

// ---------------- K4: gate + out_proj + skip. 64 l per block ----------------
__global__ __launch_bounds__(256) void k4_gate_outproj(
  const int* __restrict__ did, const float* __restrict__ Dp, const float* __restrict__ out_w,
  const float* __restrict__ skipv, const float* __restrict__ yb, const float* __restrict__ xib,
  const float* __restrict__ zb, const float* __restrict__ xnb, float* __restrict__ xmb)
{
  const int seq=blockIdx.y, j=seq>>2, p=seq&3, t=threadIdx.x;
  const int l0=blockIdx.x*64;
  const int m=mixer_of(did,j);
  __shared__ float s_yg[64][64];
  __shared__ float s_ow[32][65];
  for(int idx=t; idx<2048; idx+=256) s_ow[idx>>6][idx&63]=out_w[m*2048+idx];
  for(int it=0; it<16; ++it){
    int idx = t + it*256;
    int ll = idx>>6, dd = idx&63;
    size_t base=(size_t)seq*LSEQ*64 + (size_t)(l0+ll)*64 + dd;
    float yg=(yb[base]+Dp[m*64+dd]*xib[base])*silu_f(zb[base]);
    s_yg[ll][dd]=yg;
  }
  __syncthreads();
  const int o = t&31, grp = t>>5;
  const float sk = skipv[m];
  for(int ll=grp; ll<64; ll+=8){
    float acc=0.f;
    #pragma unroll
    for(int dd=0;dd<64;dd++) acc += s_yg[ll][dd]*s_ow[o][dd];
    size_t xidx=((size_t)j*LSEQ + l0+ll)*128 + p*32 + o;
    xmb[xidx]=acc + sk*xnb[xidx];
  }
}

// ---------------- K5: LN2 + proj, both experts, 16 l per block ----------------
__global__ __launch_bounds__(256) void k5_ln2_proj(
  const int* __restrict__ did, const float* __restrict__ ln_g, const float* __restrict__ ln_b,
  const float* __restrict__ proj_w, const float* __restrict__ proj_b,
  const float* __restrict__ xmb, float* __restrict__ out)
{
  const int b=blockIdx.y, l0=blockIdx.x*16, t=threadIdx.x;
  const int eh = t>>7, local = t&127;     // half eh handles job j=2b+eh
  const int j = 2*b+eh;
  const int m = mixer_of(did, j);
  __shared__ float s_xn[2][16][132];
  __shared__ float s_comb[16][132];
  __shared__ float s_murs[2][16][2];

  for(int idx=local; idx<2048; idx+=128){
    int ll=idx>>7, c=idx&127;
    s_xn[eh][ll][c] = xmb[((size_t)j*LSEQ + l0+ll)*128 + c];
  }
  __syncthreads();
  // LN stats: per half, 2 waves x 8 l
  {
    const int lane = t&63;
    const int g = lane&7, lw = lane>>3;
    const int ll = ((t>>6)&1)*8 + lw;
    float sum=0.f;
    #pragma unroll
    for(int k=0;k<16;k++) sum += s_xn[eh][ll][g*16+k];
    sum += __shfl_xor(sum,1); sum += __shfl_xor(sum,2); sum += __shfl_xor(sum,4);
    float mu = sum*(1.f/128.f);
    float vs=0.f;
    #pragma unroll
    for(int k=0;k<16;k++){ float dv=s_xn[eh][ll][g*16+k]-mu; vs+=dv*dv; }
    vs += __shfl_xor(vs,1); vs += __shfl_xor(vs,2); vs += __shfl_xor(vs,4);
    if(g==0){ s_murs[eh][ll][0]=mu; s_murs[eh][ll][1]=rsqrtf(vs*(1.f/128.f)+1e-5f); }
  }
  __syncthreads();
  for(int idx=local; idx<2048; idx+=128){
    int ll=idx>>7, c=idx&127;
    float xn=(s_xn[eh][ll][c]-s_murs[eh][ll][0])*s_murs[eh][ll][1]*ln_g[m*128+c]+ln_b[m*128+c];
    s_xn[eh][ll][c]=xn;
  }
  __syncthreads();
  // proj: thread o=local, 16 accumulators, stream float4 weights from L2
  float acc[16];
  #pragma unroll
  for(int ll=0;ll<16;ll++) acc[ll]=0.f;
  {
    const float4* pw4 = (const float4*)(proj_w + (size_t)m*16384 + (size_t)local*128);
    #pragma unroll 4
    for(int c4=0;c4<32;c4++){
      float4 w = pw4[c4];
      int c = c4*4;
      #pragma unroll
      for(int ll=0;ll<16;ll++){
        acc[ll] += w.x*s_xn[eh][ll][c] + w.y*s_xn[eh][ll][c+1]
                 + w.z*s_xn[eh][ll][c+2] + w.w*s_xn[eh][ll][c+3];
      }
    }
  }
  float pb_v = proj_b[m*128+local];
  if(eh==0){
    #pragma unroll
    for(int ll=0;ll<16;ll++) s_comb[ll][local]=acc[ll]+pb_v;
  }
  __syncthreads();
  if(eh==1){
    #pragma unroll
    for(int ll=0;ll<16;ll++) s_comb[ll][local]+=acc[ll]+pb_v;
  }
  __syncthreads();
  // cooperative write: rows of 16 l contiguous
  for(int idx=t; idx<2048; idx+=256){
    int o=idx>>4, ll=idx&15;
    out[((size_t)b*128+o)*LSEQ + l0+ll] = s_comb[ll][o];
  }
}

extern "C" void kernel_launch(void* const* d_in, const int* in_sizes, int n_in,
                              void* d_out, int out_size, void* d_ws, size_t ws_size,
                              hipStream_t stream) {
  const float* x      = (const float*)d_in[0];
  const int*   did    = (const int*)d_in[1];
  const float* ln_g   = (const float*)d_in[2];
  const float* ln_b   = (const float*)d_in[3];
  const float* in_w   = (const float*)d_in[4];
  const float* conv_w = (const float*)d_in[5];
  const float* conv_b = (const float*)d_in[6];
  const float* xp_w   = (const float*)d_in[7];
  const float* dt_w   = (const float*)d_in[8];
  const float* dt_b   = (const float*)d_in[9];
  const float* A_log  = (const float*)d_in[10];
  const float* Dp     = (const float*)d_in[11];
  const float* out_w  = (const float*)d_in[12];
  const float* proj_w = (const float*)d_in[13];
  const float* proj_b = (const float*)d_in[14];
  const float* skipv  = (const float*)d_in[15];
  float* out = (float*)d_out;
  float* ws  = (float*)d_ws;

  float* xnb = ws;                                   // NJ*L*128
  float* xzr = xnb + (size_t)NJ*LSEQ*128;            // NSEQ*L*64
  float* zb  = xzr + (size_t)NSEQ*LSEQ*64;           // NSEQ*L*64
  float* xib = zb  + (size_t)NSEQ*LSEQ*64;           // NSEQ*L*64
  float* dlb = xib + (size_t)NSEQ*LSEQ*64;           // NSEQ*L*64
  float* bmb = dlb + (size_t)NSEQ*LSEQ*64;           // NSEQ*L*16
  float* cmb = bmb + (size_t)NSEQ*LSEQ*16;           // NSEQ*L*16
  float* xmb = cmb + (size_t)NSEQ*LSEQ*16;           // NJ*L*128
  float* pb  = xmb + (size_t)NJ*LSEQ*128;            // NSEQ*NC*1024
  float* eb  = pb  + (size_t)NSEQ*NC*1024;           // NSEQ*NC*1024
  float* hsb = eb  + (size_t)NSEQ*NC*1024;           // NSEQ*NC*1024
  float* yb  = xzr;                                  // reuse (dead after k2)

  hipLaunchKernelGGL(k1_ln_inproj, dim3(LSEQ/32,NJ), dim3(256), 0, stream,
                     x,did,ln_g,ln_b,in_w,xnb,xzr,zb);
  hipLaunchKernelGGL(k2_conv_xproj, dim3(LSEQ/64,NSEQ), dim3(256), 0, stream,
                     did,conv_w,conv_b,xp_w,dt_w,dt_b,xzr,xib,dlb,bmb,cmb);
  hipLaunchKernelGGL(k3a_scan_pe, dim3(NC,NSEQ), dim3(1024), 0, stream,
                     did,A_log,xib,dlb,bmb,pb,eb);
  hipLaunchKernelGGL(k3b_combine, dim3(NSEQ), dim3(1024), 0, stream, pb,eb,hsb);
  hipLaunchKernelGGL(k3c_scan_y, dim3(NC,NSEQ), dim3(1024), 0, stream,
                     did,A_log,xib,dlb,bmb,cmb,hsb,yb);
  hipLaunchKernelGGL(k4_gate_outproj, dim3(LSEQ/64,NSEQ), dim3(256), 0, stream,
                     did,Dp,out_w,skipv,yb,xib,zb,xnb,xmb);
  hipLaunchKernelGGL(k5_ln2_proj, dim3(LSEQ/16,2), dim3(256), 0, stream,
                     did,ln_g,ln_b,proj_w,proj_b,xmb,out);
}